// Round 1
// baseline (487.403 us; speedup 1.0000x reference)
//
#include <hip/hip_runtime.h>

typedef float floatx16 __attribute__((ext_vector_type(16)));
typedef int   intx4    __attribute__((ext_vector_type(4)));
typedef int   intx8    __attribute__((ext_vector_type(8)));

#define GEMM_M 8192   // A*B = 4*2048
#define GEMM_N 8192   // OUT
#define GEMM_K 2048   // C
#define NT     32     // K-tiles of BK=64 bytes

// ---------------------------------------------------------------------------
// Quantize fp32 -> fp8 e4m3fn (unchanged from previous round; coalesced).
// ---------------------------------------------------------------------------
__global__ __launch_bounds__(256) void quant_e4m3(const float* __restrict__ x,
                                                  const float* __restrict__ scale,
                                                  int* __restrict__ q)
{
    const float s = scale[0];
    const int base = blockIdx.x * 1024 + threadIdx.x;
    const float4* __restrict__ x4 = (const float4*)x;
#pragma unroll
    for (int j = 0; j < 4; ++j) {
        float4 v = x4[base + j * 256];
        int p;
        p = __builtin_amdgcn_cvt_pk_fp8_f32(v.x * s, v.y * s, 0, false);
        p = __builtin_amdgcn_cvt_pk_fp8_f32(v.z * s, v.w * s, p, true);
        q[base + j * 256] = p;
    }
}

// ---------------------------------------------------------------------------
// 256x256 deep-pipelined MX-fp8 GEMM (T1+T3+T4+T5 on top of the previous
// m97-style kernel):
//   - 512 threads = 8 waves (2M x 4N), wave tile 128x64 -> 4x2 acc of 32x32.
//   - BK=64B K-tiles, 4 LDS double^2-buffers (128 KB total), prefetch depth 3.
//   - Counted vmcnt(8) at the single per-K-tile barrier; NEVER drained to 0
//     in the main loop (the previous kernel's per-tile vmcnt(0) drain was the
//     33% MfmaUtil cap). Ledger: during tile T, tiles T+1..T+3 in flight
//     (12 loads/wave); vmcnt(8) retires the oldest 4 = tile T+1. Tail peels
//     at vmcnt(4)/vmcnt(0).
//   - s_setprio(1) around the MFMA cluster (T5; pays only in phased loops).
//   - XCD-bijective blockIdx swizzle (1024 wgs % 8 == 0).
//   - Same XOR chunk swizzle as before: LDS chunk c of row r holds global
//     chunk c ^ ((r>>1)&3); global_load_lds dest stays linear (rule 21).
// A-frag (32x32x64): lane holds A[m=lane&31][k=32h+j], j=0..31 (h=lane>>5).
// C/D: col=lane&31, row=(reg&3)+8*(reg>>2)+4*h   [m74/m101]
// ---------------------------------------------------------------------------
#define GLDS(gp, lp) __builtin_amdgcn_global_load_lds( \
    (const __attribute__((address_space(1))) void*)(gp), \
    (__attribute__((address_space(3))) void*)(lp), 16, 0, 0)

__global__ __launch_bounds__(512, 2) void gemm_fp8_mx(
    const unsigned char* __restrict__ Aq,   // [M,K] fp8
    const unsigned char* __restrict__ Bq,   // [N,K] fp8
    float* __restrict__ C,                  // [M,N]
    const float* __restrict__ sa,
    const float* __restrict__ sb)
{
    extern __shared__ __align__(16) unsigned char lds[];
    unsigned char* ldsA = lds;           // 4 bufs x 16 KB
    unsigned char* ldsB = lds + 65536;   // 4 bufs x 16 KB

    const int tid  = threadIdx.x;
    const int lane = tid & 63;
    const int wave = tid >> 6;    // 0..7
    const int wm   = wave >> 2;   // 0..1 (M)
    const int wn   = wave & 3;    // 0..3 (N)

    // XCD-aware bijective swizzle over the 1024-wg grid (32x32 tiles)
    const int bid = blockIdx.x;
    const int nb  = (bid & 7) * 128 + (bid >> 3);
    const int bm  = nb >> 5;
    const int bn  = nb & 31;

    // ---- staging addresses: 4 x global_load_lds(16B) per wave per K-tile.
    // Instr covers 128 rows: row = tid>>2, lds chunk = tid&3 (linear dest);
    // global chunk = (tid&3) ^ s(row), s(r) = (r>>1)&3 = (tid>>3)&3.
    const int srow   = tid >> 2;
    const int schunk = ((tid & 3) ^ ((tid >> 3) & 3)) << 4;
    const unsigned char* gA0 = Aq + (size_t)(bm * 256 +       srow) * GEMM_K + schunk;
    const unsigned char* gA1 = Aq + (size_t)(bm * 256 + 128 + srow) * GEMM_K + schunk;
    const unsigned char* gB0 = Bq + (size_t)(bn * 256 +       srow) * GEMM_K + schunk;
    const unsigned char* gB1 = Bq + (size_t)(bn * 256 + 128 + srow) * GEMM_K + schunk;
    const int l0 = tid * 16;

    // ---- fragment addresses (per 16 KB buffer) ----
    const int mloc = lane & 31;
    const int h    = lane >> 5;
    const int swz  = (mloc >> 1) & 3;   // row offsets below are mult. of 32
    const int aoff_lo = (wm * 128 + mloc) * 64 + (((2 * h)     ^ swz) << 4);
    const int aoff_hi = (wm * 128 + mloc) * 64 + (((2 * h + 1) ^ swz) << 4);
    const int boff_lo = (wn * 64  + mloc) * 64 + (((2 * h)     ^ swz) << 4);
    const int boff_hi = (wn * 64  + mloc) * 64 + (((2 * h + 1) ^ swz) << 4);

    floatx16 acc[4][2];
#pragma unroll
    for (int i = 0; i < 4; ++i)
#pragma unroll
        for (int j = 0; j < 2; ++j)
            acc[i][j] = (floatx16)(0.0f);

#define STAGE(KT) do { \
    const int _b = (KT) & 3; \
    const size_t _ko = (size_t)(KT) * 64; \
    GLDS(gA0 + _ko, ldsA + _b * 16384 +        l0); \
    GLDS(gA1 + _ko, ldsA + _b * 16384 + 8192 + l0); \
    GLDS(gB0 + _ko, ldsB + _b * 16384 +        l0); \
    GLDS(gB1 + _ko, ldsB + _b * 16384 + 8192 + l0); \
} while (0)

#define KSTEP(KT, STAGE_STMT) do { \
    const unsigned char* _bA = ldsA + ((KT) & 3) * 16384; \
    const unsigned char* _bB = ldsB + ((KT) & 3) * 16384; \
    intx8 _a[4], _bf[2]; \
    _Pragma("unroll") \
    for (int _t = 0; _t < 4; ++_t) { \
        intx4 lo = *(const intx4*)(_bA + aoff_lo + _t * 2048); \
        intx4 hi = *(const intx4*)(_bA + aoff_hi + _t * 2048); \
        _a[_t] = __builtin_shufflevector(lo, hi, 0, 1, 2, 3, 4, 5, 6, 7); \
    } \
    _Pragma("unroll") \
    for (int _t = 0; _t < 2; ++_t) { \
        intx4 lo = *(const intx4*)(_bB + boff_lo + _t * 2048); \
        intx4 hi = *(const intx4*)(_bB + boff_hi + _t * 2048); \
        _bf[_t] = __builtin_shufflevector(lo, hi, 0, 1, 2, 3, 4, 5, 6, 7); \
    } \
    STAGE_STMT; \
    __builtin_amdgcn_s_setprio(1); \
    _Pragma("unroll") \
    for (int _i = 0; _i < 4; ++_i) \
    _Pragma("unroll") \
    for (int _j = 0; _j < 2; ++_j) \
        acc[_i][_j] = __builtin_amdgcn_mfma_scale_f32_32x32x64_f8f6f4( \
            _a[_i], _bf[_j], acc[_i][_j], \
            0, 0, 0, 0x7f7f7f7f, 0, 0x7f7f7f7f); \
    __builtin_amdgcn_s_setprio(0); \
} while (0)

#define BARRIER() do { asm volatile("" ::: "memory"); \
    __builtin_amdgcn_s_barrier(); \
    asm volatile("" ::: "memory"); } while (0)

    // prologue: tiles 0..2 in flight; land tile 0
    STAGE(0); STAGE(1); STAGE(2);
    asm volatile("s_waitcnt vmcnt(8)" ::: "memory");
    BARRIER();

#pragma unroll 1
    for (int kt = 0; kt <= NT - 4; ++kt) {
        KSTEP(kt, STAGE(kt + 3));
        asm volatile("s_waitcnt vmcnt(8)" ::: "memory");  // tile kt+1 landed
        BARRIER();
    }
    KSTEP(NT - 3, (void)0);
    asm volatile("s_waitcnt vmcnt(4)" ::: "memory");      // tile NT-2 landed
    BARRIER();
    KSTEP(NT - 2, (void)0);
    asm volatile("s_waitcnt vmcnt(0)" ::: "memory");      // tile NT-1 landed
    BARRIER();
    KSTEP(NT - 1, (void)0);

    // ---- epilogue: dequant + store ----
    const float inv = 1.0f / (sa[0] * sb[0]);
#pragma unroll
    for (int ti = 0; ti < 4; ++ti) {
        const int row0 = bm * 256 + wm * 128 + ti * 32 + 4 * h;
#pragma unroll
        for (int tj = 0; tj < 2; ++tj) {
            const int col = bn * 256 + wn * 64 + tj * 32 + mloc;
#pragma unroll
            for (int reg = 0; reg < 16; ++reg) {
                const int row = row0 + (reg & 3) + 8 * (reg >> 2);
                C[(size_t)row * GEMM_N + col] = acc[ti][tj][reg] * inv;
            }
        }
    }
}

extern "C" void kernel_launch(void* const* d_in, const int* in_sizes, int n_in,
                              void* d_out, int out_size, void* d_ws, size_t ws_size,
                              hipStream_t stream) {
    const float* x    = (const float*)d_in[0];   // [4,2048,2048]
    const float* w    = (const float*)d_in[1];   // [8192,2048]
    const float* s_in = (const float*)d_in[2];   // input_scale_e4m3
    const float* s_w  = (const float*)d_in[3];   // weight_scale_e4m3
    float* out = (float*)d_out;                  // [4,2048,8192] fp32

    unsigned char* qx = (unsigned char*)d_ws;                 // 16 MB
    unsigned char* qw = qx + (size_t)GEMM_M * GEMM_K;         // 16 MB

    quant_e4m3<<<in_sizes[0] / 4096, 256, 0, stream>>>(x, s_in, (int*)qx);
    quant_e4m3<<<in_sizes[1] / 4096, 256, 0, stream>>>(w, s_w, (int*)qw);

    static int attr_done = 0;
    if (!attr_done) {
        hipFuncSetAttribute((const void*)gemm_fp8_mx,
                            hipFuncAttributeMaxDynamicSharedMemorySize, 131072);
        attr_done = 1;
    }
    gemm_fp8_mx<<<dim3(1024), dim3(512), 131072, stream>>>(qx, qw, out, s_in, s_w);
}

// Round 2
// 478.233 us; speedup vs baseline: 1.0192x; 1.0192x over previous
//
#include <hip/hip_runtime.h>

typedef float floatx16 __attribute__((ext_vector_type(16)));
typedef int   intx4    __attribute__((ext_vector_type(4)));
typedef int   intx8    __attribute__((ext_vector_type(8)));

#define GEMM_M 8192   // A*B = 4*2048
#define GEMM_N 8192   // OUT
#define GEMM_K 2048   // C
#define NT     32     // K-tiles of BK=64 bytes

// ---------------------------------------------------------------------------
// Quantize fp32 -> fp8 e4m3fn (unchanged; coalesced float4 -> packed int).
// ---------------------------------------------------------------------------
__global__ __launch_bounds__(256) void quant_e4m3(const float* __restrict__ x,
                                                  const float* __restrict__ scale,
                                                  int* __restrict__ q)
{
    const float s = scale[0];
    const int base = blockIdx.x * 1024 + threadIdx.x;
    const float4* __restrict__ x4 = (const float4*)x;
#pragma unroll
    for (int j = 0; j < 4; ++j) {
        float4 v = x4[base + j * 256];
        int p;
        p = __builtin_amdgcn_cvt_pk_fp8_f32(v.x * s, v.y * s, 0, false);
        p = __builtin_amdgcn_cvt_pk_fp8_f32(v.z * s, v.w * s, p, true);
        q[base + j * 256] = p;
    }
}

// ---------------------------------------------------------------------------
// 256x256 MX-fp8 GEMM, m201-style 2-phase-per-K-tile interleave:
//   - 512 threads = 8 waves (2M x 4N), wave tile 128x64 -> 4x2 acc of 32x32.
//   - Per K-tile: P0 {ds_read a0,a1,b0,b1 | stage A-half kt+3 | bar |
//     lgkm(0) | 4 MFMA | bar}, P1 {ds_read a2,a3 | stage B-half kt+3 | bar |
//     lgkm(0) | 4 MFMA | vmcnt(8) | bar}.  Reads stay in flight across the
//     first barrier; counted vmcnt retires exactly one tile per K-step
//     (never 0 in the main loop).  Ledger: 12 loads in flight (tiles
//     kt+1..kt+3, 4/tile); vmcnt(8) = tile kt+1 landed. Tail: 8->4->0.
//   - 4 LDS K-tile buffers (128 KB), prefetch depth 3.
//   - XCD ordering: bm = xcd*4 + (r>>2) keeps each XCD's 2 MB A-slice L2-
//     resident; bn walked in groups of 4 -> B streamed once per XCD
//     (round-1 ordering streamed B 4x: FETCH 270 MB).
//   - XOR chunk swizzle unchanged: LDS chunk c of row r holds global chunk
//     c ^ ((r>>1)&3); glds dest linear (rule 21). Fragment b128 reads hit
//     all 32 banks exactly once per 8-lane phase.
// A-frag (32x32x64): lane holds A[m=lane&31][k=32h+j], j=0..31 (h=lane>>5).
// C/D: col=lane&31, row=(reg&3)+8*(reg>>2)+4*h   [m74/m101]
// ---------------------------------------------------------------------------
#define GLDS(gp, lp) __builtin_amdgcn_global_load_lds( \
    (const __attribute__((address_space(1))) void*)(gp), \
    (__attribute__((address_space(3))) void*)(lp), 16, 0, 0)

#define MFMA1(A_, B_, C_) __builtin_amdgcn_mfma_scale_f32_32x32x64_f8f6f4( \
    (A_), (B_), (C_), 0, 0, 0, 0x7f7f7f7f, 0, 0x7f7f7f7f)

__global__ __launch_bounds__(512, 2) void gemm_fp8_mx(
    const unsigned char* __restrict__ Aq,   // [M,K] fp8
    const unsigned char* __restrict__ Bq,   // [N,K] fp8
    float* __restrict__ C,                  // [M,N]
    const float* __restrict__ sa,
    const float* __restrict__ sb)
{
    extern __shared__ __align__(16) unsigned char lds[];
    unsigned char* ldsA = lds;           // 4 bufs x 16 KB
    unsigned char* ldsB = lds + 65536;   // 4 bufs x 16 KB

    const int tid  = threadIdx.x;
    const int lane = tid & 63;
    const int wave = tid >> 6;    // 0..7
    const int wm   = wave >> 2;   // 0..1 (M)
    const int wn   = wave & 3;    // 0..3 (N)

    // XCD-resident-A ordering over the 1024-wg grid (32x32 tiles of 256x256)
    const int bid = blockIdx.x;
    const int xcd = bid & 7;
    const int idx = bid >> 3;            // 0..127 within XCD
    const int bm  = xcd * 4 + ((idx & 15) >> 2);   // 4 contiguous A panels/XCD
    const int bn  = (idx >> 4) * 4 + (idx & 3);    // bn in groups of 4

    // ---- staging: 4 x glds(16B) per wave per K-tile (2 in P0, 2 in P1).
    // row = tid>>2, lds chunk = tid&3 (linear dest);
    // global chunk = (tid&3) ^ ((row>>1)&3) = (tid&3) ^ ((tid>>3)&3).
    const int srow   = tid >> 2;
    const int schunk = ((tid & 3) ^ ((tid >> 3) & 3)) << 4;
    const unsigned char* gA0 = Aq + (size_t)(bm * 256 +       srow) * GEMM_K + schunk;
    const unsigned char* gA1 = Aq + (size_t)(bm * 256 + 128 + srow) * GEMM_K + schunk;
    const unsigned char* gB0 = Bq + (size_t)(bn * 256 +       srow) * GEMM_K + schunk;
    const unsigned char* gB1 = Bq + (size_t)(bn * 256 + 128 + srow) * GEMM_K + schunk;
    const int l0 = tid * 16;

    // ---- fragment addresses (within a 16 KB buffer) ----
    const int mloc = lane & 31;
    const int h    = lane >> 5;
    const int swz  = (mloc >> 1) & 3;
    const int aoff_lo = (wm * 128 + mloc) * 64 + (((2 * h)     ^ swz) << 4);
    const int aoff_hi = (wm * 128 + mloc) * 64 + (((2 * h + 1) ^ swz) << 4);
    const int boff_lo = (wn * 64  + mloc) * 64 + (((2 * h)     ^ swz) << 4);
    const int boff_hi = (wn * 64  + mloc) * 64 + (((2 * h + 1) ^ swz) << 4);

    floatx16 acc[4][2];
#pragma unroll
    for (int i = 0; i < 4; ++i)
#pragma unroll
        for (int j = 0; j < 2; ++j)
            acc[i][j] = (floatx16)(0.0f);

    intx8 af0, af1, bf0, bf1;   // bf0/bf1 persist P0 -> P1

#define LDFRAG(dst, base, olo, ohi) do { \
    intx4 _lo = *(const intx4*)((base) + (olo)); \
    intx4 _hi = *(const intx4*)((base) + (ohi)); \
    (dst) = __builtin_shufflevector(_lo, _hi, 0, 1, 2, 3, 4, 5, 6, 7); \
} while (0)

#define STAGE_A(KT) do { \
    const int _b = (KT) & 3; const size_t _ko = (size_t)(KT) * 64; \
    GLDS(gA0 + _ko, ldsA + _b * 16384 +        l0); \
    GLDS(gA1 + _ko, ldsA + _b * 16384 + 8192 + l0); \
} while (0)

#define STAGE_B(KT) do { \
    const int _b = (KT) & 3; const size_t _ko = (size_t)(KT) * 64; \
    GLDS(gB0 + _ko, ldsB + _b * 16384 +        l0); \
    GLDS(gB1 + _ko, ldsB + _b * 16384 + 8192 + l0); \
} while (0)

#define P0(KT, STAGE_STMT) do { \
    const unsigned char* _bA = ldsA + ((KT) & 3) * 16384; \
    const unsigned char* _bB = ldsB + ((KT) & 3) * 16384; \
    LDFRAG(af0, _bA, aoff_lo,        aoff_hi); \
    LDFRAG(af1, _bA, aoff_lo + 2048, aoff_hi + 2048); \
    LDFRAG(bf0, _bB, boff_lo,        boff_hi); \
    LDFRAG(bf1, _bB, boff_lo + 2048, boff_hi + 2048); \
    STAGE_STMT; \
    __builtin_amdgcn_s_barrier(); \
    asm volatile("s_waitcnt lgkmcnt(0)" ::: "memory"); \
    __builtin_amdgcn_s_setprio(1); \
    acc[0][0] = MFMA1(af0, bf0, acc[0][0]); \
    acc[0][1] = MFMA1(af0, bf1, acc[0][1]); \
    acc[1][0] = MFMA1(af1, bf0, acc[1][0]); \
    acc[1][1] = MFMA1(af1, bf1, acc[1][1]); \
    __builtin_amdgcn_s_setprio(0); \
    __builtin_amdgcn_s_barrier(); \
} while (0)

#define P1(KT, STAGE_STMT, TAILWAIT) do { \
    const unsigned char* _bA = ldsA + ((KT) & 3) * 16384; \
    LDFRAG(af0, _bA, aoff_lo + 4096, aoff_hi + 4096); \
    LDFRAG(af1, _bA, aoff_lo + 6144, aoff_hi + 6144); \
    STAGE_STMT; \
    __builtin_amdgcn_s_barrier(); \
    asm volatile("s_waitcnt lgkmcnt(0)" ::: "memory"); \
    __builtin_amdgcn_s_setprio(1); \
    acc[2][0] = MFMA1(af0, bf0, acc[2][0]); \
    acc[2][1] = MFMA1(af0, bf1, acc[2][1]); \
    acc[3][0] = MFMA1(af1, bf0, acc[3][0]); \
    acc[3][1] = MFMA1(af1, bf1, acc[3][1]); \
    __builtin_amdgcn_s_setprio(0); \
    TAILWAIT; \
    __builtin_amdgcn_s_barrier(); \
} while (0)

    // prologue: tiles 0..2 in flight (12 loads); land tile 0
    STAGE_A(0); STAGE_B(0);
    STAGE_A(1); STAGE_B(1);
    STAGE_A(2); STAGE_B(2);
    asm volatile("s_waitcnt vmcnt(8)" ::: "memory");
    __builtin_amdgcn_s_barrier();

#pragma unroll 1
    for (int kt = 0; kt <= NT - 4; ++kt) {
        P0(kt, STAGE_A(kt + 3));
        P1(kt, STAGE_B(kt + 3),
           asm volatile("s_waitcnt vmcnt(8)" ::: "memory"));  // tile kt+1 landed
    }
    P0(NT - 3, (void)0);
    P1(NT - 3, (void)0, asm volatile("s_waitcnt vmcnt(4)" ::: "memory"));
    P0(NT - 2, (void)0);
    P1(NT - 2, (void)0, asm volatile("s_waitcnt vmcnt(0)" ::: "memory"));
    P0(NT - 1, (void)0);
    P1(NT - 1, (void)0, (void)0);

    // ---- epilogue: dequant + store ----
    const float inv = 1.0f / (sa[0] * sb[0]);
#pragma unroll
    for (int ti = 0; ti < 4; ++ti) {
        const int row0 = bm * 256 + wm * 128 + ti * 32 + 4 * h;
#pragma unroll
        for (int tj = 0; tj < 2; ++tj) {
            const int col = bn * 256 + wn * 64 + tj * 32 + mloc;
#pragma unroll
            for (int reg = 0; reg < 16; ++reg) {
                const int row = row0 + (reg & 3) + 8 * (reg >> 2);
                C[(size_t)row * GEMM_N + col] = acc[ti][tj][reg] * inv;
            }
        }
    }
}

extern "C" void kernel_launch(void* const* d_in, const int* in_sizes, int n_in,
                              void* d_out, int out_size, void* d_ws, size_t ws_size,
                              hipStream_t stream) {
    const float* x    = (const float*)d_in[0];   // [4,2048,2048]
    const float* w    = (const float*)d_in[1];   // [8192,2048]
    const float* s_in = (const float*)d_in[2];   // input_scale_e4m3
    const float* s_w  = (const float*)d_in[3];   // weight_scale_e4m3
    float* out = (float*)d_out;                  // [4,2048,8192] fp32

    unsigned char* qx = (unsigned char*)d_ws;                 // 16 MB
    unsigned char* qw = qx + (size_t)GEMM_M * GEMM_K;         // 16 MB

    quant_e4m3<<<in_sizes[0] / 4096, 256, 0, stream>>>(x, s_in, (int*)qx);
    quant_e4m3<<<in_sizes[1] / 4096, 256, 0, stream>>>(w, s_w, (int*)qw);

    static int attr_done = 0;
    if (!attr_done) {
        hipFuncSetAttribute((const void*)gemm_fp8_mx,
                            hipFuncAttributeMaxDynamicSharedMemorySize, 131072);
        attr_done = 1;
    }
    gemm_fp8_mx<<<dim3(1024), dim3(512), 131072, stream>>>(qx, qw, out, s_in, s_w);
}

// Round 3
// 475.079 us; speedup vs baseline: 1.0259x; 1.0066x over previous
//
#include <hip/hip_runtime.h>

typedef float floatx16 __attribute__((ext_vector_type(16)));
typedef int   intx4    __attribute__((ext_vector_type(4)));
typedef int   intx8    __attribute__((ext_vector_type(8)));

#define GEMM_M 8192   // A*B = 4*2048
#define GEMM_N 8192   // OUT
#define GEMM_K 2048   // C
#define NT     32     // K-tiles of BK=64 bytes

// ---------------------------------------------------------------------------
// Quantize fp32 -> fp8 e4m3fn (unchanged; coalesced float4 -> packed int).
// ---------------------------------------------------------------------------
__global__ __launch_bounds__(256) void quant_e4m3(const float* __restrict__ x,
                                                  const float* __restrict__ scale,
                                                  int* __restrict__ q)
{
    const float s = scale[0];
    const int base = blockIdx.x * 1024 + threadIdx.x;
    const float4* __restrict__ x4 = (const float4*)x;
#pragma unroll
    for (int j = 0; j < 4; ++j) {
        float4 v = x4[base + j * 256];
        int p;
        p = __builtin_amdgcn_cvt_pk_fp8_f32(v.x * s, v.y * s, 0, false);
        p = __builtin_amdgcn_cvt_pk_fp8_f32(v.z * s, v.w * s, p, true);
        q[base + j * 256] = p;
    }
}

// ---------------------------------------------------------------------------
// 256x256 MX-fp8 GEMM, 4 waves x 128x128 wave tiles (fragment-reuse geometry):
//   - Rounds 0-2 all hit ~3080 cyc/K-tile with 3 different schedules ->
//     LDS pipe was the binding resource (96 b128/tile @ ~16 cyc eff).
//     128x128 wave tiles cut fragment reads to 64 b128/tile (1.0 per MFMA).
//   - 256 threads = 4 waves (2M x 2N), acc 4x4 of 32x32 (256 AGPR/wave,
//     1 wave/SIMD by design; MFMA async drain + depth-3 glds prefetch hide).
//   - 2-phase K-step: P0 {ds_read A0,A1,B0..B3 | stage A(kt+3) | bar |
//     lgkm(0) | 8 MFMA | bar}, P1 {ds_read A2,A3 | stage B(kt+3) | bar |
//     lgkm(0) | 8 MFMA | vmcnt(16) | bar}. Counted vmcnt: 8 glds/tile,
//     24 in flight, vmcnt(16) = tile kt+1 landed. Tail 8->0.
//   - 4 LDS K-tile buffers (128 KB), XOR chunk swizzle: LDS chunk c of row
//     r holds global chunk c ^ ((r>>1)&3); glds dest linear (rule 21).
//   - XCD ordering (round 2, verified FETCH 270->98 MB): 4 contiguous A
//     panels per XCD, bn in groups of 4.
// A-frag (32x32x64): lane holds A[m=lane&31][k=32h+j], j=0..31 (h=lane>>5).
// C/D: col=lane&31, row=(reg&3)+8*(reg>>2)+4*h   [m74/m101]
// ---------------------------------------------------------------------------
#define GLDS(gp, lp) __builtin_amdgcn_global_load_lds( \
    (const __attribute__((address_space(1))) void*)(gp), \
    (__attribute__((address_space(3))) void*)(lp), 16, 0, 0)

#define MFMA1(A_, B_, C_) __builtin_amdgcn_mfma_scale_f32_32x32x64_f8f6f4( \
    (A_), (B_), (C_), 0, 0, 0, 0x7f7f7f7f, 0, 0x7f7f7f7f)

__global__ __launch_bounds__(256, 1) void gemm_fp8_mx(
    const unsigned char* __restrict__ Aq,   // [M,K] fp8
    const unsigned char* __restrict__ Bq,   // [N,K] fp8
    float* __restrict__ C,                  // [M,N]
    const float* __restrict__ sa,
    const float* __restrict__ sb)
{
    extern __shared__ __align__(16) unsigned char lds[];
    unsigned char* ldsA = lds;           // 4 bufs x 16 KB
    unsigned char* ldsB = lds + 65536;   // 4 bufs x 16 KB

    const int tid  = threadIdx.x;
    const int lane = tid & 63;
    const int wave = tid >> 6;    // 0..3
    const int wm   = wave >> 1;   // 0..1 (M)
    const int wn   = wave & 1;    // 0..1 (N)

    // XCD-resident-A ordering over the 1024-wg grid (32x32 tiles of 256x256)
    const int bid = blockIdx.x;
    const int xcd = bid & 7;
    const int idx = bid >> 3;            // 0..127 within XCD
    const int bm  = xcd * 4 + ((idx & 15) >> 2);   // 4 contiguous A panels/XCD
    const int bn  = (idx >> 4) * 4 + (idx & 3);    // bn in groups of 4

    // ---- staging: 8 x glds(16B) per thread per K-tile (4 A in P0, 4 B in P1).
    // glds t covers rows t*64 + (tid>>2); lds chunk = tid&3 (linear dest);
    // global chunk = (tid&3) ^ ((row>>1)&3) = (tid&3) ^ ((tid>>3)&3).
    const int srow   = tid >> 2;
    const int schunk = ((tid & 3) ^ ((tid >> 3) & 3)) << 4;
    const unsigned char* gA = Aq + (size_t)(bm * 256 + srow) * GEMM_K + schunk;
    const unsigned char* gB = Bq + (size_t)(bn * 256 + srow) * GEMM_K + schunk;
    const int l0 = tid * 16;

    // ---- fragment addresses (within a 16 KB buffer) ----
    const int mloc = lane & 31;
    const int h    = lane >> 5;
    const int swz  = (mloc >> 1) & 3;
    const int alo = (wm * 128 + mloc) * 64 + (((2 * h)     ^ swz) << 4);
    const int ahi = (wm * 128 + mloc) * 64 + (((2 * h + 1) ^ swz) << 4);
    const int blo = (wn * 128 + mloc) * 64 + (((2 * h)     ^ swz) << 4);
    const int bhi = (wn * 128 + mloc) * 64 + (((2 * h + 1) ^ swz) << 4);

    floatx16 acc[4][4];
#pragma unroll
    for (int i = 0; i < 4; ++i)
#pragma unroll
        for (int j = 0; j < 4; ++j)
            acc[i][j] = (floatx16)(0.0f);

    intx8 af0, af1, bf0, bf1, bf2, bf3;   // bf* persist P0 -> P1

#define LDFRAG(dst, base, olo, ohi) do { \
    intx4 _lo = *(const intx4*)((base) + (olo)); \
    intx4 _hi = *(const intx4*)((base) + (ohi)); \
    (dst) = __builtin_shufflevector(_lo, _hi, 0, 1, 2, 3, 4, 5, 6, 7); \
} while (0)

#define STAGE_A(KT) do { \
    const int _b = (KT) & 3; const size_t _ko = (size_t)(KT) * 64; \
    GLDS(gA + _ko,                     ldsA + _b * 16384 +         l0); \
    GLDS(gA + _ko +     64 * GEMM_K,   ldsA + _b * 16384 +  4096 + l0); \
    GLDS(gA + _ko + 2 * 64 * GEMM_K,   ldsA + _b * 16384 +  8192 + l0); \
    GLDS(gA + _ko + 3 * 64 * GEMM_K,   ldsA + _b * 16384 + 12288 + l0); \
} while (0)

#define STAGE_B(KT) do { \
    const int _b = (KT) & 3; const size_t _ko = (size_t)(KT) * 64; \
    GLDS(gB + _ko,                     ldsB + _b * 16384 +         l0); \
    GLDS(gB + _ko +     64 * GEMM_K,   ldsB + _b * 16384 +  4096 + l0); \
    GLDS(gB + _ko + 2 * 64 * GEMM_K,   ldsB + _b * 16384 +  8192 + l0); \
    GLDS(gB + _ko + 3 * 64 * GEMM_K,   ldsB + _b * 16384 + 12288 + l0); \
} while (0)

#define P0(KT, STAGE_STMT) do { \
    const unsigned char* _bA = ldsA + ((KT) & 3) * 16384; \
    const unsigned char* _bB = ldsB + ((KT) & 3) * 16384; \
    LDFRAG(af0, _bA, alo,        ahi); \
    LDFRAG(af1, _bA, alo + 2048, ahi + 2048); \
    LDFRAG(bf0, _bB, blo,        bhi); \
    LDFRAG(bf1, _bB, blo + 2048, bhi + 2048); \
    LDFRAG(bf2, _bB, blo + 4096, bhi + 4096); \
    LDFRAG(bf3, _bB, blo + 6144, bhi + 6144); \
    STAGE_STMT; \
    __builtin_amdgcn_s_barrier(); \
    asm volatile("s_waitcnt lgkmcnt(0)" ::: "memory"); \
    __builtin_amdgcn_s_setprio(1); \
    acc[0][0] = MFMA1(af0, bf0, acc[0][0]); \
    acc[0][1] = MFMA1(af0, bf1, acc[0][1]); \
    acc[0][2] = MFMA1(af0, bf2, acc[0][2]); \
    acc[0][3] = MFMA1(af0, bf3, acc[0][3]); \
    acc[1][0] = MFMA1(af1, bf0, acc[1][0]); \
    acc[1][1] = MFMA1(af1, bf1, acc[1][1]); \
    acc[1][2] = MFMA1(af1, bf2, acc[1][2]); \
    acc[1][3] = MFMA1(af1, bf3, acc[1][3]); \
    __builtin_amdgcn_s_setprio(0); \
    __builtin_amdgcn_s_barrier(); \
} while (0)

#define P1(KT, STAGE_STMT, TAILWAIT) do { \
    const unsigned char* _bA = ldsA + ((KT) & 3) * 16384; \
    LDFRAG(af0, _bA, alo + 4096, ahi + 4096); \
    LDFRAG(af1, _bA, alo + 6144, ahi + 6144); \
    STAGE_STMT; \
    __builtin_amdgcn_s_barrier(); \
    asm volatile("s_waitcnt lgkmcnt(0)" ::: "memory"); \
    __builtin_amdgcn_s_setprio(1); \
    acc[2][0] = MFMA1(af0, bf0, acc[2][0]); \
    acc[2][1] = MFMA1(af0, bf1, acc[2][1]); \
    acc[2][2] = MFMA1(af0, bf2, acc[2][2]); \
    acc[2][3] = MFMA1(af0, bf3, acc[2][3]); \
    acc[3][0] = MFMA1(af1, bf0, acc[3][0]); \
    acc[3][1] = MFMA1(af1, bf1, acc[3][1]); \
    acc[3][2] = MFMA1(af1, bf2, acc[3][2]); \
    acc[3][3] = MFMA1(af1, bf3, acc[3][3]); \
    __builtin_amdgcn_s_setprio(0); \
    TAILWAIT; \
    __builtin_amdgcn_s_barrier(); \
} while (0)

    // prologue: tiles 0..2 in flight (24 loads); land tile 0
    STAGE_A(0); STAGE_B(0);
    STAGE_A(1); STAGE_B(1);
    STAGE_A(2); STAGE_B(2);
    asm volatile("s_waitcnt vmcnt(16)" ::: "memory");
    __builtin_amdgcn_s_barrier();

#pragma unroll 1
    for (int kt = 0; kt <= NT - 4; ++kt) {
        P0(kt, STAGE_A(kt + 3));
        P1(kt, STAGE_B(kt + 3),
           asm volatile("s_waitcnt vmcnt(16)" ::: "memory"));  // tile kt+1 landed
    }
    P0(NT - 3, (void)0);
    P1(NT - 3, (void)0, asm volatile("s_waitcnt vmcnt(8)" ::: "memory"));
    P0(NT - 2, (void)0);
    P1(NT - 2, (void)0, asm volatile("s_waitcnt vmcnt(0)" ::: "memory"));
    P0(NT - 1, (void)0);
    P1(NT - 1, (void)0, (void)0);

    // ---- epilogue: dequant + store ----
    const float inv = 1.0f / (sa[0] * sb[0]);
#pragma unroll
    for (int ti = 0; ti < 4; ++ti) {
        const int row0 = bm * 256 + wm * 128 + ti * 32 + 4 * h;
#pragma unroll
        for (int tj = 0; tj < 4; ++tj) {
            const int col = bn * 256 + wn * 128 + tj * 32 + mloc;
#pragma unroll
            for (int reg = 0; reg < 16; ++reg) {
                const int row = row0 + (reg & 3) + 8 * (reg >> 2);
                C[(size_t)row * GEMM_N + col] = acc[ti][tj][reg] * inv;
            }
        }
    }
}

extern "C" void kernel_launch(void* const* d_in, const int* in_sizes, int n_in,
                              void* d_out, int out_size, void* d_ws, size_t ws_size,
                              hipStream_t stream) {
    const float* x    = (const float*)d_in[0];   // [4,2048,2048]
    const float* w    = (const float*)d_in[1];   // [8192,2048]
    const float* s_in = (const float*)d_in[2];   // input_scale_e4m3
    const float* s_w  = (const float*)d_in[3];   // weight_scale_e4m3
    float* out = (float*)d_out;                  // [4,2048,8192] fp32

    unsigned char* qx = (unsigned char*)d_ws;                 // 16 MB
    unsigned char* qw = qx + (size_t)GEMM_M * GEMM_K;         // 16 MB

    quant_e4m3<<<in_sizes[0] / 4096, 256, 0, stream>>>(x, s_in, (int*)qx);
    quant_e4m3<<<in_sizes[1] / 4096, 256, 0, stream>>>(w, s_w, (int*)qw);

    static int attr_done = 0;
    if (!attr_done) {
        hipFuncSetAttribute((const void*)gemm_fp8_mx,
                            hipFuncAttributeMaxDynamicSharedMemorySize, 131072);
        attr_done = 1;
    }
    gemm_fp8_mx<<<dim3(1024), dim3(256), 131072, stream>>>(qx, qw, out, s_in, s_w);
}

// Round 4
// 470.995 us; speedup vs baseline: 1.0348x; 1.0087x over previous
//
#include <hip/hip_runtime.h>

typedef float floatx16 __attribute__((ext_vector_type(16)));
typedef int   intx4    __attribute__((ext_vector_type(4)));
typedef int   intx8    __attribute__((ext_vector_type(8)));

#define GEMM_M 8192   // A*B = 4*2048
#define GEMM_N 8192   // OUT
#define GEMM_K 2048   // C
#define NT     32     // K-tiles of BK=64 bytes

// ---------------------------------------------------------------------------
// Quantize fp32 -> fp8 e4m3fn (unchanged; coalesced float4 -> packed int).
// ---------------------------------------------------------------------------
__global__ __launch_bounds__(256) void quant_e4m3(const float* __restrict__ x,
                                                  const float* __restrict__ scale,
                                                  int* __restrict__ q)
{
    const float s = scale[0];
    const int base = blockIdx.x * 1024 + threadIdx.x;
    const float4* __restrict__ x4 = (const float4*)x;
#pragma unroll
    for (int j = 0; j < 4; ++j) {
        float4 v = x4[base + j * 256];
        int p;
        p = __builtin_amdgcn_cvt_pk_fp8_f32(v.x * s, v.y * s, 0, false);
        p = __builtin_amdgcn_cvt_pk_fp8_f32(v.z * s, v.w * s, p, true);
        q[base + j * 256] = p;
    }
}

// ---------------------------------------------------------------------------
// 256x256 MX-fp8 GEMM with a sched_barrier(0)-PINNED K-step (the one HK
// ingredient rounds 0-3 lacked). Rounds 0-3 all compiled to the same
// serialized [reads]->[wait]->[MFMA] tile loop (~3030 cyc/tile, 35% MfmaUtil)
// because register-only MFMAs float freely past asm-volatile waits/barriers
// (rule #18) and the compiler normalized every source-level schedule.
// Pinned layout per K-tile (ONE s_barrier per tile, not four):
//   {af0,af1,bf0,bf1 reads | STAGE_A(kt+3)} || SBAR(0)
//   {af2,af3 reads        | STAGE_B(kt+3)} || SBAR(0)
//   setprio1  c1: 4 MFMA (af0,af1 x bf0,bf1)   setprio0 || SBAR(0)
//   setprio1  c2: 4 MFMA (af2,af3 x bf0,bf1)   setprio0 || SBAR(0)
//   vmcnt(8)  s_barrier
// c2's operands land while c1 drains; next tile's reads issue while c2
// drains (waves cross the barrier after ISSUING MFMAs). LDS dep-waits are
// the compiler's own tight auto-lgkmcnt; pins stop MFMA hoisting past them.
// Buffer hazard: tile kt stages (kt+3)&3 == (kt-1)&3, fully read before
// tile-(kt-1)'s end barrier. vmcnt ledger: 4 glds/wave/tile, steady
// in-flight 12, vmcnt(8) retires tile kt+1; tail 4 -> 0.
// Geometry/staging/swizzle/L2-ordering identical to round 2 (verified).
// A-frag (32x32x64): lane holds A[m=lane&31][k=32h+j], j=0..31 (h=lane>>5).
// C/D: col=lane&31, row=(reg&3)+8*(reg>>2)+4*h   [m74/m101]
// ---------------------------------------------------------------------------
#define GLDS(gp, lp) __builtin_amdgcn_global_load_lds( \
    (const __attribute__((address_space(1))) void*)(gp), \
    (__attribute__((address_space(3))) void*)(lp), 16, 0, 0)

#define MFMA1(A_, B_, C_) __builtin_amdgcn_mfma_scale_f32_32x32x64_f8f6f4( \
    (A_), (B_), (C_), 0, 0, 0, 0x7f7f7f7f, 0, 0x7f7f7f7f)

#define SBAR() __builtin_amdgcn_sched_barrier(0)

__global__ __launch_bounds__(512, 2) void gemm_fp8_mx(
    const unsigned char* __restrict__ Aq,   // [M,K] fp8
    const unsigned char* __restrict__ Bq,   // [N,K] fp8
    float* __restrict__ C,                  // [M,N]
    const float* __restrict__ sa,
    const float* __restrict__ sb)
{
    extern __shared__ __align__(16) unsigned char lds[];
    unsigned char* ldsA = lds;           // 4 bufs x 16 KB
    unsigned char* ldsB = lds + 65536;   // 4 bufs x 16 KB

    const int tid  = threadIdx.x;
    const int lane = tid & 63;
    const int wave = tid >> 6;    // 0..7
    const int wm   = wave >> 2;   // 0..1 (M)
    const int wn   = wave & 3;    // 0..3 (N)

    // XCD-resident-A ordering (round 2, verified FETCH 270->98 MB)
    const int bid = blockIdx.x;
    const int xcd = bid & 7;
    const int idx = bid >> 3;            // 0..127 within XCD
    const int bm  = xcd * 4 + ((idx & 15) >> 2);   // 4 contiguous A panels/XCD
    const int bn  = (idx >> 4) * 4 + (idx & 3);    // bn in groups of 4

    // ---- staging: 4 x glds(16B) per thread per K-tile (2 A, 2 B).
    // row = tid>>2, lds chunk = tid&3 (linear dest);
    // global chunk = (tid&3) ^ ((row>>1)&3) = (tid&3) ^ ((tid>>3)&3).
    const int srow   = tid >> 2;
    const int schunk = ((tid & 3) ^ ((tid >> 3) & 3)) << 4;
    const unsigned char* gA0 = Aq + (size_t)(bm * 256 +       srow) * GEMM_K + schunk;
    const unsigned char* gA1 = Aq + (size_t)(bm * 256 + 128 + srow) * GEMM_K + schunk;
    const unsigned char* gB0 = Bq + (size_t)(bn * 256 +       srow) * GEMM_K + schunk;
    const unsigned char* gB1 = Bq + (size_t)(bn * 256 + 128 + srow) * GEMM_K + schunk;
    const int l0 = tid * 16;

    // ---- fragment addresses (within a 16 KB buffer) ----
    const int mloc = lane & 31;
    const int h    = lane >> 5;
    const int swz  = (mloc >> 1) & 3;
    const int alo = (wm * 128 + mloc) * 64 + (((2 * h)     ^ swz) << 4);
    const int ahi = (wm * 128 + mloc) * 64 + (((2 * h + 1) ^ swz) << 4);
    const int blo = (wn * 64  + mloc) * 64 + (((2 * h)     ^ swz) << 4);
    const int bhi = (wn * 64  + mloc) * 64 + (((2 * h + 1) ^ swz) << 4);

    floatx16 acc[4][2];
#pragma unroll
    for (int i = 0; i < 4; ++i)
#pragma unroll
        for (int j = 0; j < 2; ++j)
            acc[i][j] = (floatx16)(0.0f);

    intx8 af0, af1, af2, af3, bf0, bf1;

#define LDFRAG(dst, base, olo, ohi) do { \
    intx4 _lo = *(const intx4*)((base) + (olo)); \
    intx4 _hi = *(const intx4*)((base) + (ohi)); \
    (dst) = __builtin_shufflevector(_lo, _hi, 0, 1, 2, 3, 4, 5, 6, 7); \
} while (0)

#define STAGE_A(KT) do { \
    const int _b = (KT) & 3; const size_t _ko = (size_t)(KT) * 64; \
    GLDS(gA0 + _ko, ldsA + _b * 16384 +        l0); \
    GLDS(gA1 + _ko, ldsA + _b * 16384 + 8192 + l0); \
} while (0)

#define STAGE_B(KT) do { \
    const int _b = (KT) & 3; const size_t _ko = (size_t)(KT) * 64; \
    GLDS(gB0 + _ko, ldsB + _b * 16384 +        l0); \
    GLDS(gB1 + _ko, ldsB + _b * 16384 + 8192 + l0); \
} while (0)

#define KSTEP(KT, SA_STMT, SB_STMT, TAILWAIT) do { \
    const unsigned char* _bA = ldsA + ((KT) & 3) * 16384; \
    const unsigned char* _bB = ldsB + ((KT) & 3) * 16384; \
    LDFRAG(af0, _bA, alo,        ahi); \
    LDFRAG(af1, _bA, alo + 2048, ahi + 2048); \
    LDFRAG(bf0, _bB, blo,        bhi); \
    LDFRAG(bf1, _bB, blo + 2048, bhi + 2048); \
    SA_STMT; \
    SBAR(); \
    LDFRAG(af2, _bA, alo + 4096, ahi + 4096); \
    LDFRAG(af3, _bA, alo + 6144, ahi + 6144); \
    SB_STMT; \
    SBAR(); \
    __builtin_amdgcn_s_setprio(1); \
    acc[0][0] = MFMA1(af0, bf0, acc[0][0]); \
    acc[0][1] = MFMA1(af0, bf1, acc[0][1]); \
    acc[1][0] = MFMA1(af1, bf0, acc[1][0]); \
    acc[1][1] = MFMA1(af1, bf1, acc[1][1]); \
    __builtin_amdgcn_s_setprio(0); \
    SBAR(); \
    __builtin_amdgcn_s_setprio(1); \
    acc[2][0] = MFMA1(af2, bf0, acc[2][0]); \
    acc[2][1] = MFMA1(af2, bf1, acc[2][1]); \
    acc[3][0] = MFMA1(af3, bf0, acc[3][0]); \
    acc[3][1] = MFMA1(af3, bf1, acc[3][1]); \
    __builtin_amdgcn_s_setprio(0); \
    SBAR(); \
    TAILWAIT; \
    __builtin_amdgcn_s_barrier(); \
} while (0)

    // prologue: tiles 0..2 in flight (12 loads/wave); land tile 0
    STAGE_A(0); STAGE_B(0);
    STAGE_A(1); STAGE_B(1);
    STAGE_A(2); STAGE_B(2);
    asm volatile("s_waitcnt vmcnt(8)" ::: "memory");
    __builtin_amdgcn_s_barrier();

#pragma unroll 1
    for (int kt = 0; kt <= NT - 4; ++kt) {
        KSTEP(kt, STAGE_A(kt + 3), STAGE_B(kt + 3),
              asm volatile("s_waitcnt vmcnt(8)" ::: "memory"));  // tile kt+1 landed
    }
    KSTEP(NT - 3, (void)0, (void)0,
          asm volatile("s_waitcnt vmcnt(4)" ::: "memory"));      // tile NT-2 landed
    KSTEP(NT - 2, (void)0, (void)0,
          asm volatile("s_waitcnt vmcnt(0)" ::: "memory"));      // tile NT-1 landed
    KSTEP(NT - 1, (void)0, (void)0, (void)0);

    // ---- epilogue: dequant + store ----
    const float inv = 1.0f / (sa[0] * sb[0]);
#pragma unroll
    for (int ti = 0; ti < 4; ++ti) {
        const int row0 = bm * 256 + wm * 128 + ti * 32 + 4 * h;
#pragma unroll
        for (int tj = 0; tj < 2; ++tj) {
            const int col = bn * 256 + wn * 64 + tj * 32 + mloc;
#pragma unroll
            for (int reg = 0; reg < 16; ++reg) {
                const int row = row0 + (reg & 3) + 8 * (reg >> 2);
                C[(size_t)row * GEMM_N + col] = acc[ti][tj][reg] * inv;
            }
        }
    }
}

extern "C" void kernel_launch(void* const* d_in, const int* in_sizes, int n_in,
                              void* d_out, int out_size, void* d_ws, size_t ws_size,
                              hipStream_t stream) {
    const float* x    = (const float*)d_in[0];   // [4,2048,2048]
    const float* w    = (const float*)d_in[1];   // [8192,2048]
    const float* s_in = (const float*)d_in[2];   // input_scale_e4m3
    const float* s_w  = (const float*)d_in[3];   // weight_scale_e4m3
    float* out = (float*)d_out;                  // [4,2048,8192] fp32

    unsigned char* qx = (unsigned char*)d_ws;                 // 16 MB
    unsigned char* qw = qx + (size_t)GEMM_M * GEMM_K;         // 16 MB

    quant_e4m3<<<in_sizes[0] / 4096, 256, 0, stream>>>(x, s_in, (int*)qx);
    quant_e4m3<<<in_sizes[1] / 4096, 256, 0, stream>>>(w, s_w, (int*)qw);

    static int attr_done = 0;
    if (!attr_done) {
        hipFuncSetAttribute((const void*)gemm_fp8_mx,
                            hipFuncAttributeMaxDynamicSharedMemorySize, 131072);
        attr_done = 1;
    }
    gemm_fp8_mx<<<dim3(1024), dim3(512), 131072, stream>>>(qx, qw, out, s_in, s_w);
}